// Round 3
// baseline (176.786 us; speedup 1.0000x reference)
//
#include <hip/hip_runtime.h>
#include <math.h>

#define TPB 256

// R = (1 - b*th2) I + b * v v^T + a * K, K = skew(v).
// Fast-math version: rsqrt instead of sqrt + exact divisions; native sin/cos.
// Matches reference semantics incl. small-angle branch (a=1, b=0.5).
__device__ __forceinline__ void rodrigues(float v0, float v1, float v2, float R[9]) {
    float th2 = v0 * v0 + v1 * v1 + v2 * v2;
    bool  sm  = th2 < 1e-12f;            // th < 1e-6
    float g   = sm ? 1.0f : th2;
    float inv = rsqrtf(g);               // v_rsq_f32
    float th  = g * inv;                 // sqrt(g)
    float s   = __sinf(th);              // v_sin_f32 path
    float c   = __cosf(th);
    float a   = sm ? 1.0f : s * inv;
    float b   = sm ? 0.5f : (1.0f - c) * (inv * inv);
    float cc  = 1.0f - b * th2;
    R[0] = cc + b * v0 * v0;      R[1] = b * v0 * v1 - a * v2;  R[2] = b * v0 * v2 + a * v1;
    R[3] = b * v0 * v1 + a * v2;  R[4] = cc + b * v1 * v1;      R[5] = b * v1 * v2 - a * v0;
    R[6] = b * v0 * v2 - a * v1;  R[7] = b * v1 * v2 + a * v0;  R[8] = cc + b * v2 * v2;
}

__global__ __launch_bounds__(TPB) void aff_kernel(
    const float* __restrict__ trans,
    const float* __restrict__ rotat,
    const float* __restrict__ sdir,
    const float* __restrict__ scal,
    float4* __restrict__ out,
    int B)
{
    // Per-wave output slab (3 KB each): wave-local transpose, NO __syncthreads.
    __shared__ float4 s_out[TPB / 64][192];

    const int tid   = threadIdx.x;
    const int w     = tid >> 6;
    const int l     = tid & 63;
    const int ebase = blockIdx.x * TPB + (w << 6);   // wave's first element
    if (ebase >= B) return;      // B % 64 == 0 -> waves are fully active or fully absent
    const int e  = ebase + l;
    const int b3 = 3 * e;

    // 12 independent scalar loads -> good MLP; lines fully covered collectively.
    float t0 = trans[b3], t1 = trans[b3 + 1], t2 = trans[b3 + 2];
    float r0 = rotat[b3], r1 = rotat[b3 + 1], r2 = rotat[b3 + 2];
    float u0 = sdir [b3], u1 = sdir [b3 + 1], u2 = sdir [b3 + 2];
    float s0 = scal [b3], s1 = scal [b3 + 1], s2 = scal [b3 + 2];

    float R[9], U[9];
    rodrigues(r0, r1, r2, R);
    rodrigues(u0, u1, u2, U);
    float d0 = __expf(s0);
    float d1 = __expf(s1);
    float d2 = __expf(s2);

    // W = U * diag(d)
    float W[9];
#pragma unroll
    for (int i = 0; i < 3; ++i) {
        W[3*i+0] = U[3*i+0] * d0;
        W[3*i+1] = U[3*i+1] * d1;
        W[3*i+2] = U[3*i+2] * d2;
    }
    // S = W * U^T
    float S[9];
#pragma unroll
    for (int i = 0; i < 3; ++i)
#pragma unroll
        for (int j = 0; j < 3; ++j)
            S[3*i+j] = W[3*i+0]*U[3*j+0] + W[3*i+1]*U[3*j+1] + W[3*i+2]*U[3*j+2];
    // M = R * S
    float M[9];
#pragma unroll
    for (int i = 0; i < 3; ++i)
#pragma unroll
        for (int j = 0; j < 3; ++j)
            M[3*i+j] = R[3*i+0]*S[0+j] + R[3*i+1]*S[3+j] + R[3*i+2]*S[6+j];

    // Wave-local transpose: 3 aligned float4 LDS writes per lane...
    float4* slab = s_out[w];
    slab[3*l + 0] = make_float4(M[0], M[1], M[2], t0);
    slab[3*l + 1] = make_float4(M[3], M[4], M[5], t1);
    slab[3*l + 2] = make_float4(M[6], M[7], M[8], t2);

    __builtin_amdgcn_wave_barrier();   // compiler fence; wave64 lockstep + in-order DS

    // ...then 3 perfectly coalesced 1 KB global stores per wave.
    const int ob = 3 * ebase;          // float4 base of this wave's output
#pragma unroll
    for (int k = 0; k < 3; ++k) {
        int idx = (k << 6) + l;
        out[ob + idx] = slab[idx];
    }
}

extern "C" void kernel_launch(void* const* d_in, const int* in_sizes, int n_in,
                              void* d_out, int out_size, void* d_ws, size_t ws_size,
                              hipStream_t stream) {
    const float* tr = (const float*)d_in[0];
    const float* ro = (const float*)d_in[1];
    const float* sd = (const float*)d_in[2];
    const float* sc = (const float*)d_in[3];
    float4* out = (float4*)d_out;

    int B = in_sizes[0] / 3;                 // 2,000,000 elements
    int blocks = (B + TPB - 1) / TPB;
    aff_kernel<<<blocks, TPB, 0, stream>>>(tr, ro, sd, sc, out, B);
}